// Round 2
// baseline (73.197 us; speedup 1.0000x reference)
//
#include <hip/hip_runtime.h>
#include <stdint.h>

#define NXD 2048
#define NYD 2048
#define DIMD 28
#define ROW_DW 12   // packed dwords per row (10 used, padded to 3x uint4)

// class nibble table: v -> class, classes = [1,1,1,0,0,0,0,2] packed low->high
#define CLS_TABLE 0x20000111u

// ws layout (uint32): rows 0..2047 = r-packs, rows 2048..4095 = t-packs.
// Row bits: [0,224) value one-hot at d*8+v ; [224,308) class one-hot at 224+d*3+c.

__global__ __launch_bounds__(256) void pack_kernel(
    const int* __restrict__ set_r, const int* __restrict__ set_t,
    uint32_t* __restrict__ ws)
{
    const int row = blockIdx.x * 256 + threadIdx.x;          // 0..4095
    const int* src = (row < NXD) ? (set_r + row * DIMD)
                                 : (set_t + (size_t)(row - NXD) * DIMD);
    int vals[DIMD];
    const int4* s4 = (const int4*)src;                        // 28 ints = 7x int4, 16B aligned
    #pragma unroll
    for (int q = 0; q < 7; ++q) {
        int4 v = s4[q];
        vals[4*q+0] = v.x; vals[4*q+1] = v.y;
        vals[4*q+2] = v.z; vals[4*q+3] = v.w;
    }

    // eq one-hot: 4x u64 (word index compile-time since 8d..8d+7 never crosses 64)
    unsigned long long e0 = 0, e1 = 0, e2 = 0, e3 = 0;
    // class one-hot (3 bits/pos, 84 bits): 2x u64, runtime select only at d=21
    unsigned long long c0 = 0, c1 = 0;
    #pragma unroll
    for (int d = 0; d < DIMD; ++d) {
        const int v = vals[d];
        const int be = d * 8 + v;                    // 0..223
        const unsigned long long bit = 1ull << (be & 63);
        switch (be >> 6) {                           // compile-time per d
            case 0: e0 |= bit; break;
            case 1: e1 |= bit; break;
            case 2: e2 |= bit; break;
            default: e3 |= bit; break;
        }
        const int c = (CLS_TABLE >> (4 * v)) & 0xF;  // 0..2
        const int bc = d * 3 + c;                    // 0..83
        if (bc < 64) c0 |= 1ull << bc;
        else         c1 |= 1ull << (bc - 64);
    }

    // assemble 12 dwords: w0..w6 = eq bits 0..223, w7..w9 = cls bits, w10..11 = 0
    uint32_t w0 = (uint32_t)e0, w1 = (uint32_t)(e0 >> 32);
    uint32_t w2 = (uint32_t)e1, w3 = (uint32_t)(e1 >> 32);
    uint32_t w4 = (uint32_t)e2, w5 = (uint32_t)(e2 >> 32);
    uint32_t w6 = (uint32_t)e3;                       // bits 192..223 (hi 32 of e3 unused)
    uint32_t w7 = (uint32_t)c0, w8 = (uint32_t)(c0 >> 32);
    uint32_t w9 = (uint32_t)c1;                       // cls bits 64..83

    uint4* dst = (uint4*)(ws + (size_t)row * ROW_DW);
    dst[0] = make_uint4(w0, w1, w2, w3);
    dst[1] = make_uint4(w4, w5, w6, w7);
    dst[2] = make_uint4(w8, w9, 0u, 0u);
}

// Block = 256 threads = 4 waves. Tile: 32 i-rows x 256 j-cols.
// wave w -> i-rows [blockIdx.y*32 + 8w, +8); lane -> 4 consecutive j (float4 store).
// r-pack loads are wave-uniform (scalarizable); t-packs live in registers. No LDS.
__global__ __launch_bounds__(256) void dist_kernel(
    const uint32_t* __restrict__ ws, const float* __restrict__ sigma_p,
    float* __restrict__ out)
{
    const int lane = threadIdx.x & 63;
    const int wave = threadIdx.x >> 6;
    const int i_base = blockIdx.y * 32 + wave * 8;
    const int j_base = blockIdx.x * 256 + lane * 4;

    // load 4 t-packs (rows j_base..j_base+3) into registers: 12 x uint4
    const uint4* tp = (const uint4*)(ws + (size_t)(NXD + j_base) * ROW_DW);
    uint4 T[4][3];
    #pragma unroll
    for (int s = 0; s < 4; ++s) {
        T[s][0] = tp[s*3 + 0];
        T[s][1] = tp[s*3 + 1];
        T[s][2] = tp[s*3 + 2];
    }

    const float sg = sigma_p[0];
    // out = exp(-((56 - s)/28)^2 / (2 sigma^2)) = exp(-(56-s)^2 * k)
    const float k = 1.0f / (2.0f * sg * sg * (float)(DIMD * DIMD));

    const uint4* rp = (const uint4*)ws;
    #pragma unroll
    for (int ii = 0; ii < 8; ++ii) {
        const int i = i_base + ii;               // wave-uniform
        const uint4 R0 = rp[i*3 + 0];
        const uint4 R1 = rp[i*3 + 1];
        const uint4 R2 = rp[i*3 + 2];
        float4 res;
        #pragma unroll
        for (int s = 0; s < 4; ++s) {
            const int sum =
                __popc(R0.x & T[s][0].x) + __popc(R0.y & T[s][0].y) +
                __popc(R0.z & T[s][0].z) + __popc(R0.w & T[s][0].w) +
                __popc(R1.x & T[s][1].x) + __popc(R1.y & T[s][1].y) +
                __popc(R1.z & T[s][1].z) + __popc(R1.w & T[s][1].w) +
                __popc(R2.x & T[s][2].x) + __popc(R2.y & T[s][2].y);
            const float c = (float)(56 - sum);
            (&res.x)[s] = __expf(-c * c * k);
        }
        *(float4*)(out + (size_t)i * NYD + j_base) = res;
    }
}

extern "C" void kernel_launch(void* const* d_in, const int* in_sizes, int n_in,
                              void* d_out, int out_size, void* d_ws, size_t ws_size,
                              hipStream_t stream) {
    const int*   set_r = (const int*)d_in[0];
    const int*   set_t = (const int*)d_in[1];
    const float* sigma = (const float*)d_in[2];
    float*       out   = (float*)d_out;
    uint32_t*    ws    = (uint32_t*)d_ws;

    // pack all 4096 rows (r then t) into ws
    pack_kernel<<<dim3((NXD + NYD) / 256), dim3(256), 0, stream>>>(set_r, set_t, ws);

    // 32x256 tiles -> grid (8, 64) = 512 blocks
    dist_kernel<<<dim3(NYD / 256, NXD / 32), dim3(256), 0, stream>>>(ws, sigma, out);
}

// Round 3
// 67.446 us; speedup vs baseline: 1.0853x; 1.0853x over previous
//
#include <hip/hip_runtime.h>
#include <stdint.h>

#define NXD 2048
#define NYD 2048
#define DIMD 28
// class nibble table: v -> class, classes = [1,1,1,0,0,0,0,2] packed low->high
#define CLS_TABLE 0x20000111u

// Pack one row of 28 values (each 0..7) into 10 used dwords:
//   bits [0,224): value one-hot at d*8+v        (words 0..6)
//   bits [0,84) of cls mask: class one-hot d*3+c (words 7..9)
// popcount(AND of packs) = eq_cnt + cls_cnt.
__device__ __forceinline__ void pack_row(const int* __restrict__ src,
                                         uint32_t* __restrict__ w /*[12]*/) {
    int vals[DIMD];
    const int4* s4 = (const int4*)src;   // 28 ints = 7x int4, rows 112B -> 16B aligned
#pragma unroll
    for (int q = 0; q < 7; ++q) {
        int4 t = s4[q];
        vals[4*q+0] = t.x; vals[4*q+1] = t.y;
        vals[4*q+2] = t.z; vals[4*q+3] = t.w;
    }
    unsigned long long e0=0, e1=0, e2=0, e3=0, c0=0, c1=0;
#pragma unroll
    for (int d = 0; d < DIMD; ++d) {
        const int v = vals[d];
        // (d*8)&63 and the word index are compile-time after unroll (no crossing)
        const unsigned long long eb = 1ull << (((d*8) & 63) + v);
        if      (d < 8)  e0 |= eb;
        else if (d < 16) e1 |= eb;
        else if (d < 24) e2 |= eb;
        else             e3 |= eb;
        const int c = (CLS_TABLE >> (4*v)) & 0xF;   // 0..2
        if      (d*3 + 2 < 64) c0 |= 1ull << (d*3 + c);
        else if (d*3 >= 64)    c1 |= 1ull << (d*3 - 64 + c);
        else {                                  // d == 21: bits 63..65 straddle
            const unsigned long long b = 1ull << c;
            c0 |= (b & 1ull) << 63;             // c==0 -> bit 63
            c1 |= b >> 1;                       // c==1/2 -> bits 0/1
        }
    }
    w[0]=(uint32_t)e0; w[1]=(uint32_t)(e0>>32);
    w[2]=(uint32_t)e1; w[3]=(uint32_t)(e1>>32);
    w[4]=(uint32_t)e2; w[5]=(uint32_t)(e2>>32);
    w[6]=(uint32_t)e3;                          // bits 192..223
    w[7]=(uint32_t)c0; w[8]=(uint32_t)(c0>>32);
    w[9]=(uint32_t)c1;
    w[10]=0u; w[11]=0u;
}

// Single fused kernel. Block = 256 threads, tile 32 i-rows x 256 j-cols.
// Phase 1: thread tid packs t-row j0+tid (tid<32 also packs r-row i0+tid) into LDS.
// Phase 2: thread holds 4 t-packs (local rows lane+64s -> bank-balanced b128 reads)
// in registers; r-packs read wave-uniform (LDS broadcast, conflict-free).
__global__ __launch_bounds__(256) void setdist_kernel(
    const int* __restrict__ set_r, const int* __restrict__ set_t,
    const float* __restrict__ sigma_p, float* __restrict__ out)
{
    __shared__ uint32_t t_pk[256][12];   // 12 KB
    __shared__ uint32_t r_pk[32][12];    // 1.5 KB

    const int tid = threadIdx.x;
    const int i0 = blockIdx.y * 32;
    const int j0 = blockIdx.x * 256;

    {
        uint32_t w[12];
        pack_row(set_t + (size_t)(j0 + tid) * DIMD, w);
        uint4* dst = (uint4*)t_pk[tid];
        dst[0] = make_uint4(w[0], w[1], w[2], w[3]);
        dst[1] = make_uint4(w[4], w[5], w[6], w[7]);
        dst[2] = make_uint4(w[8], w[9], 0u, 0u);
    }
    if (tid < 32) {
        uint32_t w[12];
        pack_row(set_r + (size_t)(i0 + tid) * DIMD, w);
        uint4* dst = (uint4*)r_pk[tid];
        dst[0] = make_uint4(w[0], w[1], w[2], w[3]);
        dst[1] = make_uint4(w[4], w[5], w[6], w[7]);
        dst[2] = make_uint4(w[8], w[9], 0u, 0u);
    }

    const float sg = sigma_p[0];
    // out = exp(-((56-s)/28)^2 / (2 sigma^2)) = exp(-(56-s)^2 * k)
    const float k = 1.0f / (2.0f * sg * sg * (float)(DIMD * DIMD));

    __syncthreads();

    const int lane = tid & 63;
    const int wave = tid >> 6;

    // 4 t-packs in registers; rows lane + 64*s -> lane stride 12 dw -> all 32
    // banks hit exactly 8x per b128 wave-read (structural minimum, no penalty)
    uint4 T[4][3];
#pragma unroll
    for (int s = 0; s < 4; ++s) {
        const uint4* tp = (const uint4*)t_pk[lane + 64*s];
        T[s][0] = tp[0]; T[s][1] = tp[1]; T[s][2] = tp[2];
    }

    float* obase = out + (size_t)(i0 + wave * 8) * NYD + j0 + lane;

#pragma unroll
    for (int ii = 0; ii < 8; ++ii) {
        const uint4* rp = (const uint4*)r_pk[wave * 8 + ii];  // wave-uniform
        const uint4 R0 = rp[0], R1 = rp[1], R2 = rp[2];
#pragma unroll
        for (int s = 0; s < 4; ++s) {
            const int sum =
                __popc(R0.x & T[s][0].x) + __popc(R0.y & T[s][0].y) +
                __popc(R0.z & T[s][0].z) + __popc(R0.w & T[s][0].w) +
                __popc(R1.x & T[s][1].x) + __popc(R1.y & T[s][1].y) +
                __popc(R1.z & T[s][1].z) + __popc(R1.w & T[s][1].w) +
                __popc(R2.x & T[s][2].x) + __popc(R2.y & T[s][2].y);
            const float c = (float)(56 - sum);
            // 64 lanes -> 256 B contiguous dword store, fully coalesced
            obase[(size_t)ii * NYD + 64 * s] = __expf(-c * c * k);
        }
    }
}

extern "C" void kernel_launch(void* const* d_in, const int* in_sizes, int n_in,
                              void* d_out, int out_size, void* d_ws, size_t ws_size,
                              hipStream_t stream) {
    const int*   set_r = (const int*)d_in[0];
    const int*   set_t = (const int*)d_in[1];
    const float* sigma = (const float*)d_in[2];
    float*       out   = (float*)d_out;

    // 32x256 tiles -> grid (8, 64) = 512 blocks, one launch
    setdist_kernel<<<dim3(NYD / 256, NXD / 32), dim3(256), 0, stream>>>(
        set_r, set_t, sigma, out);
}